// Round 10
// baseline (187.554 us; speedup 1.0000x reference)
//
#include <hip/hip_runtime.h>
#include <hip/hip_cooperative_groups.h>
#include <math.h>

namespace cg = cooperative_groups;

#define NN 100000
#define EE 1600000
#define HH 128
#define RR 500
#define AA 16
#define LN_EPS 1e-5f

// Bucketing: nodes -> 391 buckets of 256; payload packs (src<<8 | dst&255) in u32.
#define BSH 8
#define NPB 256
#define NB 391                   // ceil(100000/256)
#define MAXPB 4608               // mean 4096, +8 sigma
#define NWG 256                  // one block per CU, cooperative co-resident
#define TPB 1024
#define EPW 6252                 // ceil(EE/NWG) rounded to mult of 4
#define NZW 64                   // zpart slices (8 k-rows each, covers 500)

// ---------------- fused cooperative kernel ----------------

__global__ __launch_bounds__(TPB) void k_fused(
    const float* __restrict__ nf, const int* __restrict__ srcp, const int* __restrict__ dstp,
    const float* __restrict__ esn,
    const float* __restrict__ gcn_w, const float* __restrict__ gcn_b,
    const float* __restrict__ ln_w, const float* __restrict__ ln_b,
    const float* __restrict__ fc1_w, const float* __restrict__ fc1_b,
    const float* __restrict__ fc2_w, const float* __restrict__ fc2_b,
    unsigned int* __restrict__ gctr, float* __restrict__ S, float* __restrict__ T2,
    float* __restrict__ zpart, unsigned int* __restrict__ payload,
    float* __restrict__ rsv, float* __restrict__ g, float* __restrict__ out)
{
    cg::grid_group grid = cg::this_grid();
    const int wg = blockIdx.x, t = threadIdx.x;

    __shared__ union {
        struct { unsigned int hist[512], rank[512], hbase[512]; } sc;          // 6 KB
        struct { unsigned int hist[NPB]; } bd;                                  // 1 KB
        struct { float agg[NPB * 2]; float shSf[HH]; float shw[16]; } ba;       // 2.6 KB
        struct { float psum[8][HH]; float pooled[HH]; float z[HH];
                 float logits[AA]; float red[2]; } fin;                         // 5.2 KB
    } u;

    // ---- P0: WG0 zeroes gctr(512)+S(128)+T2(1); WGs 1..64 compute zpart ----
    if (wg == 0) {
        for (int j = t; j < 641; j += TPB) gctr[j] = 0u;   // gctr|S|T2 contiguous
    } else if (wg <= NZW) {
        const int sl = wg - 1;
        const int k0 = sl * 8, k1 = min(k0 + 8, RR);
        if (t < HH) {
            float acc = 0.f;
            for (int k = k0; k < k1; ++k)
                acc = fmaf(esn[k], fc1_w[(size_t)(HH + k) * HH + t], acc);
            zpart[(size_t)sl * HH + t] = acc;              // slice 63 stores 0
        }
    }
    grid.sync();

    // ---- P1: scatter edges into dst buckets ----
    {
        if (t < 512) { u.sc.hist[t] = 0u; u.sc.rank[t] = 0u; u.sc.hbase[t] = 0u; }
        __syncthreads();
        const int e0 = wg * EPW;
        const int ecnt = max(0, min(EPW, EE - e0));        // mult of 4
        const int nv = ecnt >> 2;
        const int4* d4 = reinterpret_cast<const int4*>(dstp + e0);
        const int4* s4 = reinterpret_cast<const int4*>(srcp + e0);

        for (int k = t; k < nv; k += TPB) {
            int4 d = d4[k];
            atomicAdd(&u.sc.hist[((unsigned)d.x) >> BSH], 1u);
            atomicAdd(&u.sc.hist[((unsigned)d.y) >> BSH], 1u);
            atomicAdd(&u.sc.hist[((unsigned)d.z) >> BSH], 1u);
            atomicAdd(&u.sc.hist[((unsigned)d.w) >> BSH], 1u);
        }
        __syncthreads();
        if (t < NB && u.sc.hist[t] > 0u) u.sc.hbase[t] = atomicAdd(&gctr[t], u.sc.hist[t]);
        __syncthreads();
        for (int k = t; k < nv; k += TPB) {
            int4 d = d4[k];
            int4 s = s4[k];
            #define EMIT(SS, DD) { \
                unsigned int dd = (unsigned)(DD), ss = (unsigned)(SS); \
                unsigned int b = dd >> BSH; \
                unsigned int r = atomicAdd(&u.sc.rank[b], 1u); \
                unsigned int slot = u.sc.hbase[b] + r; \
                if (slot < MAXPB) payload[(size_t)b * MAXPB + slot] = (ss << BSH) | (dd & (NPB - 1)); }
            EMIT(s.x, d.x) EMIT(s.y, d.y) EMIT(s.z, d.z) EMIT(s.w, d.w)
            #undef EMIT
        }
    }
    grid.sync();

    // ---- P2: per-bucket degree histogram -> rsv, g ----
    for (int b = wg; b < NB; b += NWG) {
        if (t < NPB) u.bd.hist[t] = 0u;
        __syncthreads();
        const unsigned int cnt = min(gctr[b], (unsigned int)MAXPB);
        const unsigned int* pl = payload + (size_t)b * MAXPB;
        const uint4* pl4 = reinterpret_cast<const uint4*>(pl);
        const unsigned int nv2 = cnt >> 2;
        for (unsigned int k = t; k < nv2; k += TPB) {
            uint4 p = pl4[k];
            atomicAdd(&u.bd.hist[p.x & (NPB - 1)], 1u);
            atomicAdd(&u.bd.hist[p.y & (NPB - 1)], 1u);
            atomicAdd(&u.bd.hist[p.z & (NPB - 1)], 1u);
            atomicAdd(&u.bd.hist[p.w & (NPB - 1)], 1u);
        }
        for (unsigned int k = (nv2 << 2) + t; k < cnt; k += TPB)
            atomicAdd(&u.bd.hist[pl[k] & (NPB - 1)], 1u);
        __syncthreads();
        if (t < NPB) {
            int node = (b << BSH) + t;
            if (node < NN) {
                float df = 1.0f + (float)u.bd.hist[t];
                float rs = rsqrtf(df);
                rsv[node] = rs;
                float2 f = *reinterpret_cast<const float2*>(&nf[2 * node]);
                float2 gv; gv.x = rs * f.x; gv.y = rs * f.y;
                *reinterpret_cast<float2*>(&g[2 * node]) = gv;
            }
        }
        __syncthreads();
    }
    grid.sync();

    // ---- P3: per-bucket aggregation + GCN channel pass; S/T2 once per WG ----
    {
        const int ch = t & (HH - 1), slot = t >> 7;
        const float w0 = gcn_w[ch], w1 = gcn_w[HH + ch], bb = gcn_b[ch];
        float accS = 0.f, accT2 = 0.f;
        if (t < HH) u.ba.shSf[t] = 0.f;
        for (int b = wg; b < NB; b += NWG) {
            if (t < NPB * 2) u.ba.agg[t] = 0.f;
            __syncthreads();
            const unsigned int cnt = min(gctr[b], (unsigned int)MAXPB);
            const unsigned int* pl = payload + (size_t)b * MAXPB;
            const uint4* pl4 = reinterpret_cast<const uint4*>(pl);
            const unsigned int nv2 = cnt >> 2;
            for (unsigned int k = t; k < nv2; k += TPB) {
                uint4 p = pl4[k];
                #define ACC(P) { \
                    unsigned int s = (P) >> BSH, dl = (P) & (NPB - 1); \
                    float2 gv = *reinterpret_cast<const float2*>(&g[2 * s]); \
                    atomicAdd(&u.ba.agg[dl],       gv.x); \
                    atomicAdd(&u.ba.agg[NPB + dl], gv.y); }
                ACC(p.x) ACC(p.y) ACC(p.z) ACC(p.w)
                #undef ACC
            }
            for (unsigned int k = (nv2 << 2) + t; k < cnt; k += TPB) {
                unsigned int p = pl[k];
                unsigned int s = p >> BSH, dl = p & (NPB - 1);
                float2 gv = *reinterpret_cast<const float2*>(&g[2 * s]);
                atomicAdd(&u.ba.agg[dl],       gv.x);
                atomicAdd(&u.ba.agg[NPB + dl], gv.y);
            }
            __syncthreads();

            const int nvalid = min(NPB, NN - (b << BSH));
            if (t < nvalid) {
                int node = (b << BSH) + t;
                float rs = rsv[node];
                float2 gv = *reinterpret_cast<const float2*>(&g[2 * node]);
                u.ba.agg[t]       = rs * (u.ba.agg[t]       + gv.x);
                u.ba.agg[NPB + t] = rs * (u.ba.agg[NPB + t] + gv.y);
            }
            __syncthreads();

            for (int j = slot; j < nvalid; j += 8) {
                float x = fmaf(u.ba.agg[j], w0, fmaf(u.ba.agg[NPB + j], w1, bb));
                float r = fmaxf(x, 0.f);
                accS  += r;
                accT2 += r * r;
            }
            __syncthreads();
        }
        atomicAdd(&u.ba.shSf[ch], accS);
        float v = accT2;
        for (int o = 32; o; o >>= 1) v += __shfl_down(v, o, 64);
        if ((t & 63) == 0) u.ba.shw[t >> 6] = v;
        __syncthreads();
        if (t < HH) atomicAdd(&S[t], u.ba.shSf[t]);
        if (t == 0) {
            float s2 = 0.f;
            #pragma unroll
            for (int w = 0; w < 16; ++w) s2 += u.ba.shw[w];
            atomicAdd(T2, s2);
        }
    }
    grid.sync();

    // ---- P4: WG0 tail: LN-collapse + fc1 + fc2 + log_softmax ----
    if (wg == 0) {
        const int ch = t & (HH - 1), sl = t >> 7;
        if (t < HH) {
            float s = S[t];
            u.fin.pooled[t] = s;
            float vv = s;
            for (int o = 32; o; o >>= 1) vv += __shfl_down(vv, o, 64);
            if ((t & 63) == 0) u.fin.red[t >> 6] = vv;
        }
        __syncthreads();
        const float T1 = u.fin.red[0] + u.fin.red[1];
        const float T2v = *T2;
        const float cntf = (float)NN * (float)HH;
        const float mean = T1 / cntf;
        const float var  = T2v / cntf - mean * mean;
        const float denom = sqrtf(var) + LN_EPS;
        if (t < HH)
            u.fin.pooled[t] = ln_w[t] * (u.fin.pooled[t] - (float)NN * mean) / denom + (float)NN * ln_b[t];
        __syncthreads();

        float acc = 0.f;
        for (int k = sl * 16; k < sl * 16 + 16; ++k)
            acc = fmaf(u.fin.pooled[k], fc1_w[(size_t)k * HH + ch], acc);
        for (int w = sl * 8; w < sl * 8 + 8; ++w)
            acc += zpart[(size_t)w * HH + ch];
        u.fin.psum[sl][ch] = acc;
        __syncthreads();
        if (t < HH) {
            float a = fc1_b[t];
            #pragma unroll
            for (int k = 0; k < 8; ++k) a += u.fin.psum[k][t];
            u.fin.z[t] = fmaxf(a, 0.f);
        }
        __syncthreads();

        if (t < AA) {
            float l = fc2_b[t];
            for (int j = 0; j < HH; ++j)
                l = fmaf(u.fin.z[j], fc2_w[j * AA + t], l);
            u.fin.logits[t] = l;
        }
        __syncthreads();

        if (t == 0) {
            float m = u.fin.logits[0];
            for (int a = 1; a < AA; ++a) m = fmaxf(m, u.fin.logits[a]);
            float sum = 0.f;
            for (int a = 0; a < AA; ++a) sum += expf(u.fin.logits[a] - m);
            float lse = m + logf(sum);
            for (int a = 0; a < AA; ++a) out[a] = u.fin.logits[a] - lse;
        }
    }
}

// ---------------- fallback path (round-2 known-good) ----------------

__global__ void k_initf(unsigned int* __restrict__ p, int n) {
    int i = blockIdx.x * blockDim.x + threadIdx.x;
    int stride = gridDim.x * blockDim.x;
    for (int j = i; j < n; j += stride) p[j] = 0u;
}

__global__ void k_deg1(const int* __restrict__ dst, int* __restrict__ deg, int e) {
    int i = blockIdx.x * blockDim.x + threadIdx.x;
    if (i < e) atomicAdd(&deg[dst[i]], 1);
}

__global__ void k_g1(const int* __restrict__ deg, const float* __restrict__ nf,
                     float* __restrict__ degf, float* __restrict__ g, int n) {
    int i = blockIdx.x * blockDim.x + threadIdx.x;
    if (i < n) {
        float df = (float)(1 + deg[i]);
        degf[i] = df;
        float rs = rsqrtf(df);
        float2 f = *reinterpret_cast<const float2*>(&nf[2 * i]);
        float2 gv; gv.x = rs * f.x; gv.y = rs * f.y;
        *reinterpret_cast<float2*>(&g[2 * i]) = gv;
    }
}

__global__ void k_edge1(const int* __restrict__ src, const int* __restrict__ dst,
                        const float* __restrict__ g, float* __restrict__ B, int e) {
    int i = blockIdx.x * blockDim.x + threadIdx.x;
    if (i < e) {
        int s = src[i], d = dst[i];
        float2 gv = *reinterpret_cast<const float2*>(&g[2 * s]);
        atomicAdd(&B[2 * d],     gv.x);
        atomicAdd(&B[2 * d + 1], gv.y);
    }
}

__global__ void k_node(const float* __restrict__ nf, const float* __restrict__ degf,
                       const float* __restrict__ B,
                       const float* __restrict__ gcn_w, const float* __restrict__ gcn_b,
                       float* __restrict__ S, float* __restrict__ T2, int n) {
    const int ch   = threadIdx.x & (HH - 1);
    const int slot = threadIdx.x >> 7;
    const float w0 = gcn_w[ch];
    const float w1 = gcn_w[HH + ch];
    const float b  = gcn_b[ch];
    float accS = 0.f, accT2 = 0.f;
    for (int i = blockIdx.x * 2 + slot; i < n; i += gridDim.x * 2) {
        float df   = degf[i];
        float invd = 1.0f / df;
        float rs   = rsqrtf(df);
        float2 bv = *reinterpret_cast<const float2*>(&B[2 * i]);
        float2 f  = *reinterpret_cast<const float2*>(&nf[2 * i]);
        float b0 = rs * bv.x + f.x * invd;
        float b1 = rs * bv.y + f.y * invd;
        float xv = fmaf(b0, w0, fmaf(b1, w1, b));
        float r  = fmaxf(xv, 0.f);
        accS  += r;
        accT2 += r * r;
    }
    __shared__ float shS[HH];
    if (slot == 1) shS[ch] = accS;
    __syncthreads();
    if (slot == 0) atomicAdd(&S[ch], accS + shS[ch]);
    float v = accT2;
    for (int o = 32; o; o >>= 1) v += __shfl_down(v, o, 64);
    __shared__ float shw[4];
    if ((threadIdx.x & 63) == 0) shw[threadIdx.x >> 6] = v;
    __syncthreads();
    if (threadIdx.x == 0) atomicAdd(T2, shw[0] + shw[1] + shw[2] + shw[3]);
}

__global__ void k_final(const float* __restrict__ S, const float* __restrict__ T2ptr,
                        const float* __restrict__ esn,
                        const float* __restrict__ ln_w, const float* __restrict__ ln_b,
                        const float* __restrict__ fc1_w, const float* __restrict__ fc1_b,
                        const float* __restrict__ fc2_w, const float* __restrict__ fc2_b,
                        float* __restrict__ out) {
    const int t = threadIdx.x;
    __shared__ float sh_pooled[HH];
    __shared__ float sh_z[HH];
    __shared__ float sh_logits[AA];
    __shared__ float shred[2];

    float s = S[t];
    float v = s;
    for (int o = 32; o; o >>= 1) v += __shfl_down(v, o, 64);
    if ((t & 63) == 0) shred[t >> 6] = v;
    __syncthreads();
    const float T1 = shred[0] + shred[1];
    const float T2 = *T2ptr;
    const float cnt = (float)NN * (float)HH;
    const float mean = T1 / cnt;
    const float var  = T2 / cnt - mean * mean;
    const float denom = sqrtf(var) + LN_EPS;
    sh_pooled[t] = ln_w[t] * (s - (float)NN * mean) / denom + (float)NN * ln_b[t];
    __syncthreads();

    float acc = fc1_b[t];
    for (int k = 0; k < HH; ++k)
        acc = fmaf(sh_pooled[k], fc1_w[k * HH + t], acc);
    for (int k = 0; k < RR; ++k)
        acc = fmaf(esn[k], fc1_w[(HH + k) * HH + t], acc);
    sh_z[t] = fmaxf(acc, 0.f);
    __syncthreads();

    if (t < AA) {
        float l = fc2_b[t];
        for (int j = 0; j < HH; ++j)
            l = fmaf(sh_z[j], fc2_w[j * AA + t], l);
        sh_logits[t] = l;
    }
    __syncthreads();

    if (t == 0) {
        float m = sh_logits[0];
        for (int a = 1; a < AA; ++a) m = fmaxf(m, sh_logits[a]);
        float sum = 0.f;
        for (int a = 0; a < AA; ++a) sum += expf(sh_logits[a] - m);
        float lse = m + logf(sum);
        for (int a = 0; a < AA; ++a) out[a] = sh_logits[a] - lse;
    }
}

extern "C" void kernel_launch(void* const* d_in, const int* in_sizes, int n_in,
                              void* d_out, int out_size, void* d_ws, size_t ws_size,
                              hipStream_t stream) {
    const float* nf     = (const float*)d_in[0];
    const int*   ei     = (const int*)d_in[1];
    const float* esn    = (const float*)d_in[2];
    const float* gcn_w  = (const float*)d_in[3];
    const float* gcn_b  = (const float*)d_in[4];
    const float* ln_w   = (const float*)d_in[5];
    const float* ln_b   = (const float*)d_in[6];
    const float* fc1_w  = (const float*)d_in[7];
    const float* fc1_b  = (const float*)d_in[8];
    const float* fc2_w  = (const float*)d_in[9];
    const float* fc2_b  = (const float*)d_in[10];
    float* out = (float*)d_out;
    float* ws  = (float*)d_ws;

    // Layout (word offsets):
    //   gctr:0(512) | S:512(128) | T2:640(1) | zpart:644(64*128) | payload | rsv | g
    const size_t OFF_S       = 512;
    const size_t OFF_T2      = OFF_S + HH;                          // 640
    const size_t OFF_ZPART   = ((OFF_T2 + 1 + 3) & ~(size_t)3);     // 644
    const size_t OFF_PAYLOAD = OFF_ZPART + (size_t)NZW * HH;        // 8836 (mult of 4)
    const size_t OFF_RSV     = OFF_PAYLOAD + (size_t)NB * MAXPB;
    const size_t OFF_G       = OFF_RSV + NN;                        // even -> float2 ok
    const size_t NEED_BKT    = (OFF_G + 2 * (size_t)NN) * 4;

    if (ws_size >= NEED_BKT) {
        unsigned int* gctr    = (unsigned int*)ws;
        float*        S       = ws + OFF_S;
        float*        T2      = ws + OFF_T2;
        float*        zpart   = ws + OFF_ZPART;
        unsigned int* payload = (unsigned int*)ws + OFF_PAYLOAD;
        float*        rsv     = ws + OFF_RSV;
        float*        g       = ws + OFF_G;

        const int* srcp = ei;
        const int* dstp = ei + EE;
        void* args[] = {
            (void*)&nf, (void*)&srcp, (void*)&dstp, (void*)&esn,
            (void*)&gcn_w, (void*)&gcn_b, (void*)&ln_w, (void*)&ln_b,
            (void*)&fc1_w, (void*)&fc1_b, (void*)&fc2_w, (void*)&fc2_b,
            (void*)&gctr, (void*)&S, (void*)&T2, (void*)&zpart,
            (void*)&payload, (void*)&rsv, (void*)&g, (void*)&out
        };
        hipLaunchCooperativeKernel((const void*)k_fused, dim3(NWG), dim3(TPB),
                                   args, 0, stream);
    } else {
        // Fallback: known-good atomic path.
        int*   deg  = (int*)ws;
        float* B    = ws + NN;
        float* S    = ws + 3 * (size_t)NN;
        float* T2   = ws + 3 * (size_t)NN + 128;
        float* degf = ws + 3 * (size_t)NN + 130;
        float* g    = ws + 4 * (size_t)NN + 130;
        const int eb = (EE + 255) / 256;
        const int nb = (NN + 255) / 256;
        hipLaunchKernelGGL(k_initf, dim3(2048), dim3(256), 0, stream, (unsigned int*)ws, 3 * NN + 129);
        hipLaunchKernelGGL(k_deg1,  dim3(eb),   dim3(256), 0, stream, ei + EE, deg, EE);
        hipLaunchKernelGGL(k_g1,    dim3(nb),   dim3(256), 0, stream, deg, nf, degf, g, NN);
        hipLaunchKernelGGL(k_edge1, dim3(eb),   dim3(256), 0, stream, ei, ei + EE, g, B, EE);
        hipLaunchKernelGGL(k_node,  dim3(512),  dim3(256), 0, stream, nf, degf, B, gcn_w, gcn_b, S, T2, NN);
        hipLaunchKernelGGL(k_final, dim3(1),    dim3(128), 0, stream,
                           S, T2, esn, ln_w, ln_b, fc1_w, fc1_b, fc2_w, fc2_b, out);
    }
}

// Round 11
// 143.876 us; speedup vs baseline: 1.3036x; 1.3036x over previous
//
#include <hip/hip_runtime.h>
#include <math.h>

#define NN 100000
#define EE 1600000
#define HH 128
#define RR 500
#define AA 16
#define LN_EPS 1e-5f

// Bucketing: nodes -> 391 buckets of 256; payload packs (src<<8 | dst&255) in u32.
#define BSH 8
#define NPB 256
#define NB 391                   // ceil(100000/256)
#define MAXPB 4608               // mean 4096, +8 sigma
#define EPW 8192                 // edges per scatter workgroup (r8-proven)
#define SCT 512                  // scatter threads
#define NWG_SC ((EE + EPW - 1) / EPW)   // 196
#define NZW 64                   // zpart slices (8 k-rows each, covers 500)

// WG0: zero gctr/S/T2/done. WGs 1..64: zpart[w][ch] = sum_k esn[k]*fc1_w[(HH+k)*HH+ch].
__global__ __launch_bounds__(256) void k_init_esn(unsigned int* __restrict__ zero_region,
                                                  const float* __restrict__ esn,
                                                  const float* __restrict__ fc1_w,
                                                  float* __restrict__ zpart) {
    const int w = blockIdx.x, t = threadIdx.x;
    if (w == 0) {
        for (int j = t; j < 642; j += 256) zero_region[j] = 0u;   // gctr|S|T2|done
        return;
    }
    const int sl = w - 1;                 // 0..63
    const int k0 = sl * 8;
    const int k1 = min(k0 + 8, RR);
    if (t < HH) {
        float acc = 0.f;
        for (int k = k0; k < k1; ++k)
            acc = fmaf(esn[k], fc1_w[(size_t)(HH + k) * HH + t], acc);
        zpart[(size_t)sl * HH + t] = acc;
    }
}

// Bucket edges by dst: LDS bucket histogram -> one reserve atomic per (WG,bucket)
// -> per-edge LDS rank atomic + direct global payload write.
__global__ __launch_bounds__(SCT) void k_scatter(const int* __restrict__ src,
                                                 const int* __restrict__ dst,
                                                 unsigned int* __restrict__ gctr,
                                                 unsigned int* __restrict__ payload) {
    __shared__ unsigned int hist[512], rank[512], hbase[512];
    const int t = threadIdx.x;
    hist[t] = 0u; rank[t] = 0u; hbase[t] = 0u;
    __syncthreads();
    const int e0 = blockIdx.x * EPW;
    const int ecnt = max(0, min(EPW, EE - e0));   // mult of 4
    const int nv = ecnt >> 2;
    const int4* d4 = reinterpret_cast<const int4*>(dst + e0);
    const int4* s4 = reinterpret_cast<const int4*>(src + e0);

    for (int k = t; k < nv; k += SCT) {
        int4 d = d4[k];
        atomicAdd(&hist[((unsigned)d.x) >> BSH], 1u);
        atomicAdd(&hist[((unsigned)d.y) >> BSH], 1u);
        atomicAdd(&hist[((unsigned)d.z) >> BSH], 1u);
        atomicAdd(&hist[((unsigned)d.w) >> BSH], 1u);
    }
    __syncthreads();

    if (t < NB && hist[t] > 0u) hbase[t] = atomicAdd(&gctr[t], hist[t]);
    __syncthreads();

    for (int k = t; k < nv; k += SCT) {
        int4 d = d4[k];
        int4 s = s4[k];
        #define EMIT(SS, DD) { \
            unsigned int dd = (unsigned)(DD), ss = (unsigned)(SS); \
            unsigned int b = dd >> BSH; \
            unsigned int r = atomicAdd(&rank[b], 1u); \
            unsigned int slot = hbase[b] + r; \
            if (slot < MAXPB) payload[(size_t)b * MAXPB + slot] = (ss << BSH) | (dd & (NPB - 1)); }
        EMIT(s.x, d.x) EMIT(s.y, d.y) EMIT(s.z, d.z) EMIT(s.w, d.w)
        #undef EMIT
    }
}

// Per bucket, 1024 threads: LDS degree histogram; write rsv = rsqrt(deg), g = rsv*f.
__global__ __launch_bounds__(1024) void k_bdeg_g(const unsigned int* __restrict__ gctr,
                                                 const unsigned int* __restrict__ payload,
                                                 const float* __restrict__ nf,
                                                 float* __restrict__ rsv, float* __restrict__ g) {
    __shared__ unsigned int hist[NPB];
    const int b = blockIdx.x, t = threadIdx.x;
    if (t < NPB) hist[t] = 0u;
    __syncthreads();
    const unsigned int cnt = min(gctr[b], (unsigned int)MAXPB);
    const unsigned int* pl = payload + (size_t)b * MAXPB;
    const uint4* pl4 = reinterpret_cast<const uint4*>(pl);
    const unsigned int nv = cnt >> 2;
    for (unsigned int k = t; k < nv; k += 1024) {
        uint4 p = pl4[k];
        atomicAdd(&hist[p.x & (NPB - 1)], 1u);
        atomicAdd(&hist[p.y & (NPB - 1)], 1u);
        atomicAdd(&hist[p.z & (NPB - 1)], 1u);
        atomicAdd(&hist[p.w & (NPB - 1)], 1u);
    }
    for (unsigned int k = (nv << 2) + t; k < cnt; k += 1024)
        atomicAdd(&hist[pl[k] & (NPB - 1)], 1u);
    __syncthreads();
    if (t < NPB) {
        int node = (b << BSH) + t;
        if (node < NN) {
            float df = 1.0f + (float)hist[t];
            float rs = rsqrtf(df);
            rsv[node] = rs;
            float2 f = *reinterpret_cast<const float2*>(&nf[2 * node]);
            float2 gv; gv.x = rs * f.x; gv.y = rs * f.y;
            *reinterpret_cast<float2*>(&g[2 * node]) = gv;
        }
    }
}

// Per bucket, 1024 threads: aggregate g[src] into x/y LDS planes, fold self-loop,
// GCN channel pass + relu; atomic S/T2; LAST block runs the FC tail in-place.
__global__ __launch_bounds__(1024) void k_bagg_node(const unsigned int* __restrict__ gctr,
        const unsigned int* __restrict__ payload,
        const float* __restrict__ g, const float* __restrict__ rsv,
        const float* __restrict__ gcn_w, const float* __restrict__ gcn_b,
        float* __restrict__ S, float* __restrict__ T2, unsigned int* __restrict__ done,
        const float* __restrict__ zpart,
        const float* __restrict__ ln_w, const float* __restrict__ ln_b,
        const float* __restrict__ fc1_w, const float* __restrict__ fc1_b,
        const float* __restrict__ fc2_w, const float* __restrict__ fc2_b,
        float* __restrict__ out) {
    __shared__ union {
        struct { float agg[NPB * 2]; float shSf[HH]; float shw[16]; } ba;
        struct { float psum[8][HH]; float pooled[HH]; float z[HH];
                 float logits[AA]; float red[2]; } fin;
    } u;
    __shared__ int s_last;
    const int b = blockIdx.x, t = threadIdx.x;
    if (t < NPB * 2) u.ba.agg[t] = 0.f;
    if (t < HH) u.ba.shSf[t] = 0.f;
    __syncthreads();
    const unsigned int cnt = min(gctr[b], (unsigned int)MAXPB);
    const unsigned int* pl = payload + (size_t)b * MAXPB;
    const uint4* pl4 = reinterpret_cast<const uint4*>(pl);
    const unsigned int nv = cnt >> 2;
    for (unsigned int k = t; k < nv; k += 1024) {
        uint4 p = pl4[k];
        #define ACC(P) { \
            unsigned int s = (P) >> BSH, dl = (P) & (NPB - 1); \
            float2 gv = *reinterpret_cast<const float2*>(&g[2 * s]); \
            atomicAdd(&u.ba.agg[dl],       gv.x); \
            atomicAdd(&u.ba.agg[NPB + dl], gv.y); }
        ACC(p.x) ACC(p.y) ACC(p.z) ACC(p.w)
        #undef ACC
    }
    for (unsigned int k = (nv << 2) + t; k < cnt; k += 1024) {
        unsigned int p = pl[k];
        unsigned int s = p >> BSH, dl = p & (NPB - 1);
        float2 gv = *reinterpret_cast<const float2*>(&g[2 * s]);
        atomicAdd(&u.ba.agg[dl],       gv.x);
        atomicAdd(&u.ba.agg[NPB + dl], gv.y);
    }
    __syncthreads();

    const int nvalid = min(NPB, NN - (b << BSH));
    if (t < nvalid) {
        int node = (b << BSH) + t;
        float rs = rsv[node];
        float2 gv = *reinterpret_cast<const float2*>(&g[2 * node]);
        u.ba.agg[t]       = rs * (u.ba.agg[t]       + gv.x);
        u.ba.agg[NPB + t] = rs * (u.ba.agg[NPB + t] + gv.y);
    }
    __syncthreads();

    const int ch = t & (HH - 1), slot = t >> 7;
    {
        const float w0 = gcn_w[ch], w1 = gcn_w[HH + ch], bb = gcn_b[ch];
        float accS = 0.f, accT2 = 0.f;
        for (int j = slot; j < nvalid; j += 8) {
            float x = fmaf(u.ba.agg[j], w0, fmaf(u.ba.agg[NPB + j], w1, bb));
            float r = fmaxf(x, 0.f);
            accS  += r;
            accT2 += r * r;
        }
        atomicAdd(&u.ba.shSf[ch], accS);
        float v = accT2;
        for (int o = 32; o; o >>= 1) v += __shfl_down(v, o, 64);
        if ((t & 63) == 0) u.ba.shw[t >> 6] = v;
        __syncthreads();
        if (t < HH) atomicAdd(&S[t], u.ba.shSf[t]);
        if (t == 0) {
            float s2 = 0.f;
            #pragma unroll
            for (int w = 0; w < 16; ++w) s2 += u.ba.shw[w];
            atomicAdd(T2, s2);
        }
    }
    // ---- last-block election (S/T2 adds drained by syncthreads' vmcnt wait) ----
    __syncthreads();
    __threadfence();
    if (t == 0) {
        unsigned int old = atomicAdd(done, 1u);
        s_last = (old == NB - 1) ? 1 : 0;
    }
    __syncthreads();
    if (!s_last) return;

    // ---- tail (r8 k_final2 body), agent-scope atomic loads for S/T2 ----
    const int sl = t >> 7;
    if (t < HH) {
        float s = __hip_atomic_load(&S[t], __ATOMIC_RELAXED, __HIP_MEMORY_SCOPE_AGENT);
        u.fin.pooled[t] = s;
        float vv = s;
        for (int o = 32; o; o >>= 1) vv += __shfl_down(vv, o, 64);
        if ((t & 63) == 0) u.fin.red[t >> 6] = vv;
    }
    __syncthreads();
    const float T1 = u.fin.red[0] + u.fin.red[1];
    const float T2v = __hip_atomic_load(T2, __ATOMIC_RELAXED, __HIP_MEMORY_SCOPE_AGENT);
    const float cntf = (float)NN * (float)HH;
    const float mean = T1 / cntf;
    const float var  = T2v / cntf - mean * mean;
    const float denom = sqrtf(var) + LN_EPS;
    if (t < HH)
        u.fin.pooled[t] = ln_w[t] * (u.fin.pooled[t] - (float)NN * mean) / denom + (float)NN * ln_b[t];
    __syncthreads();

    float acc = 0.f;
    for (int k = sl * 16; k < sl * 16 + 16; ++k)
        acc = fmaf(u.fin.pooled[k], fc1_w[(size_t)k * HH + ch], acc);
    for (int w = sl * 8; w < sl * 8 + 8; ++w)
        acc += zpart[(size_t)w * HH + ch];
    u.fin.psum[sl][ch] = acc;
    __syncthreads();
    if (t < HH) {
        float a = fc1_b[t];
        #pragma unroll
        for (int k = 0; k < 8; ++k) a += u.fin.psum[k][t];
        u.fin.z[t] = fmaxf(a, 0.f);
    }
    __syncthreads();

    if (t < AA) {
        float l = fc2_b[t];
        for (int j = 0; j < HH; ++j)
            l = fmaf(u.fin.z[j], fc2_w[j * AA + t], l);
        u.fin.logits[t] = l;
    }
    __syncthreads();

    if (t == 0) {
        float m = u.fin.logits[0];
        for (int a = 1; a < AA; ++a) m = fmaxf(m, u.fin.logits[a]);
        float sum = 0.f;
        for (int a = 0; a < AA; ++a) sum += expf(u.fin.logits[a] - m);
        float lse = m + logf(sum);
        for (int a = 0; a < AA; ++a) out[a] = u.fin.logits[a] - lse;
    }
}

// ---------------- fallback path (round-2 known-good) ----------------

__global__ void k_initf(unsigned int* __restrict__ p, int n) {
    int i = blockIdx.x * blockDim.x + threadIdx.x;
    int stride = gridDim.x * blockDim.x;
    for (int j = i; j < n; j += stride) p[j] = 0u;
}

__global__ void k_deg1(const int* __restrict__ dst, int* __restrict__ deg, int e) {
    int i = blockIdx.x * blockDim.x + threadIdx.x;
    if (i < e) atomicAdd(&deg[dst[i]], 1);
}

__global__ void k_g1(const int* __restrict__ deg, const float* __restrict__ nf,
                     float* __restrict__ degf, float* __restrict__ g, int n) {
    int i = blockIdx.x * blockDim.x + threadIdx.x;
    if (i < n) {
        float df = (float)(1 + deg[i]);
        degf[i] = df;
        float rs = rsqrtf(df);
        float2 f = *reinterpret_cast<const float2*>(&nf[2 * i]);
        float2 gv; gv.x = rs * f.x; gv.y = rs * f.y;
        *reinterpret_cast<float2*>(&g[2 * i]) = gv;
    }
}

__global__ void k_edge1(const int* __restrict__ src, const int* __restrict__ dst,
                        const float* __restrict__ g, float* __restrict__ B, int e) {
    int i = blockIdx.x * blockDim.x + threadIdx.x;
    if (i < e) {
        int s = src[i], d = dst[i];
        float2 gv = *reinterpret_cast<const float2*>(&g[2 * s]);
        atomicAdd(&B[2 * d],     gv.x);
        atomicAdd(&B[2 * d + 1], gv.y);
    }
}

__global__ void k_node(const float* __restrict__ nf, const float* __restrict__ degf,
                       const float* __restrict__ B,
                       const float* __restrict__ gcn_w, const float* __restrict__ gcn_b,
                       float* __restrict__ S, float* __restrict__ T2, int n) {
    const int ch   = threadIdx.x & (HH - 1);
    const int slot = threadIdx.x >> 7;
    const float w0 = gcn_w[ch];
    const float w1 = gcn_w[HH + ch];
    const float b  = gcn_b[ch];
    float accS = 0.f, accT2 = 0.f;
    for (int i = blockIdx.x * 2 + slot; i < n; i += gridDim.x * 2) {
        float df   = degf[i];
        float invd = 1.0f / df;
        float rs   = rsqrtf(df);
        float2 bv = *reinterpret_cast<const float2*>(&B[2 * i]);
        float2 f  = *reinterpret_cast<const float2*>(&nf[2 * i]);
        float b0 = rs * bv.x + f.x * invd;
        float b1 = rs * bv.y + f.y * invd;
        float xv = fmaf(b0, w0, fmaf(b1, w1, b));
        float r  = fmaxf(xv, 0.f);
        accS  += r;
        accT2 += r * r;
    }
    __shared__ float shS[HH];
    if (slot == 1) shS[ch] = accS;
    __syncthreads();
    if (slot == 0) atomicAdd(&S[ch], accS + shS[ch]);
    float v = accT2;
    for (int o = 32; o; o >>= 1) v += __shfl_down(v, o, 64);
    __shared__ float shw[4];
    if ((threadIdx.x & 63) == 0) shw[threadIdx.x >> 6] = v;
    __syncthreads();
    if (threadIdx.x == 0) atomicAdd(T2, shw[0] + shw[1] + shw[2] + shw[3]);
}

__global__ void k_final(const float* __restrict__ S, const float* __restrict__ T2ptr,
                        const float* __restrict__ esn,
                        const float* __restrict__ ln_w, const float* __restrict__ ln_b,
                        const float* __restrict__ fc1_w, const float* __restrict__ fc1_b,
                        const float* __restrict__ fc2_w, const float* __restrict__ fc2_b,
                        float* __restrict__ out) {
    const int t = threadIdx.x;
    __shared__ float sh_pooled[HH];
    __shared__ float sh_z[HH];
    __shared__ float sh_logits[AA];
    __shared__ float shred[2];

    float s = S[t];
    float v = s;
    for (int o = 32; o; o >>= 1) v += __shfl_down(v, o, 64);
    if ((t & 63) == 0) shred[t >> 6] = v;
    __syncthreads();
    const float T1 = shred[0] + shred[1];
    const float T2 = *T2ptr;
    const float cnt = (float)NN * (float)HH;
    const float mean = T1 / cnt;
    const float var  = T2 / cnt - mean * mean;
    const float denom = sqrtf(var) + LN_EPS;
    sh_pooled[t] = ln_w[t] * (s - (float)NN * mean) / denom + (float)NN * ln_b[t];
    __syncthreads();

    float acc = fc1_b[t];
    for (int k = 0; k < HH; ++k)
        acc = fmaf(sh_pooled[k], fc1_w[k * HH + t], acc);
    for (int k = 0; k < RR; ++k)
        acc = fmaf(esn[k], fc1_w[(HH + k) * HH + t], acc);
    sh_z[t] = fmaxf(acc, 0.f);
    __syncthreads();

    if (t < AA) {
        float l = fc2_b[t];
        for (int j = 0; j < HH; ++j)
            l = fmaf(sh_z[j], fc2_w[j * AA + t], l);
        sh_logits[t] = l;
    }
    __syncthreads();

    if (t == 0) {
        float m = sh_logits[0];
        for (int a = 1; a < AA; ++a) m = fmaxf(m, sh_logits[a]);
        float sum = 0.f;
        for (int a = 0; a < AA; ++a) sum += expf(sh_logits[a] - m);
        float lse = m + logf(sum);
        for (int a = 0; a < AA; ++a) out[a] = sh_logits[a] - lse;
    }
}

extern "C" void kernel_launch(void* const* d_in, const int* in_sizes, int n_in,
                              void* d_out, int out_size, void* d_ws, size_t ws_size,
                              hipStream_t stream) {
    const float* nf     = (const float*)d_in[0];
    const int*   ei     = (const int*)d_in[1];
    const float* esn    = (const float*)d_in[2];
    const float* gcn_w  = (const float*)d_in[3];
    const float* gcn_b  = (const float*)d_in[4];
    const float* ln_w   = (const float*)d_in[5];
    const float* ln_b   = (const float*)d_in[6];
    const float* fc1_w  = (const float*)d_in[7];
    const float* fc1_b  = (const float*)d_in[8];
    const float* fc2_w  = (const float*)d_in[9];
    const float* fc2_b  = (const float*)d_in[10];
    float* out = (float*)d_out;
    float* ws  = (float*)d_ws;

    // Layout (word offsets):
    //   gctr:0(512) | S:512(128) | T2:640 | done:641 | zpart:644(64*128) | payload | rsv | g
    const size_t OFF_S       = 512;
    const size_t OFF_T2      = OFF_S + HH;                          // 640
    const size_t OFF_DONE    = OFF_T2 + 1;                          // 641
    const size_t OFF_ZPART   = 644;
    const size_t OFF_PAYLOAD = OFF_ZPART + (size_t)NZW * HH;        // 8836 (mult of 4)
    const size_t OFF_RSV     = OFF_PAYLOAD + (size_t)NB * MAXPB;
    const size_t OFF_G       = OFF_RSV + NN;                        // even -> float2 ok
    const size_t NEED_BKT    = (OFF_G + 2 * (size_t)NN) * 4;

    if (ws_size >= NEED_BKT) {
        unsigned int* gctr    = (unsigned int*)ws;
        float*        S       = ws + OFF_S;
        float*        T2      = ws + OFF_T2;
        unsigned int* done    = (unsigned int*)ws + OFF_DONE;
        float*        zpart   = ws + OFF_ZPART;
        unsigned int* payload = (unsigned int*)ws + OFF_PAYLOAD;
        float*        rsv     = ws + OFF_RSV;
        float*        g       = ws + OFF_G;

        hipLaunchKernelGGL(k_init_esn,  dim3(NZW + 1), dim3(256),  0, stream, (unsigned int*)ws, esn, fc1_w, zpart);
        hipLaunchKernelGGL(k_scatter,   dim3(NWG_SC),  dim3(SCT),  0, stream, ei, ei + EE, gctr, payload);
        hipLaunchKernelGGL(k_bdeg_g,    dim3(NB),      dim3(1024), 0, stream, gctr, payload, nf, rsv, g);
        hipLaunchKernelGGL(k_bagg_node, dim3(NB),      dim3(1024), 0, stream,
                           gctr, payload, g, rsv, gcn_w, gcn_b, S, T2, done, zpart,
                           ln_w, ln_b, fc1_w, fc1_b, fc2_w, fc2_b, out);
    } else {
        // Fallback: known-good atomic path.
        int*   deg  = (int*)ws;
        float* B    = ws + NN;
        float* S    = ws + 3 * (size_t)NN;
        float* T2   = ws + 3 * (size_t)NN + 128;
        float* degf = ws + 3 * (size_t)NN + 130;
        float* g    = ws + 4 * (size_t)NN + 130;
        const int eb = (EE + 255) / 256;
        const int nb = (NN + 255) / 256;
        hipLaunchKernelGGL(k_initf, dim3(2048), dim3(256), 0, stream, (unsigned int*)ws, 3 * NN + 129);
        hipLaunchKernelGGL(k_deg1,  dim3(eb),   dim3(256), 0, stream, ei + EE, deg, EE);
        hipLaunchKernelGGL(k_g1,    dim3(nb),   dim3(256), 0, stream, deg, nf, degf, g, NN);
        hipLaunchKernelGGL(k_edge1, dim3(eb),   dim3(256), 0, stream, ei, ei + EE, g, B, EE);
        hipLaunchKernelGGL(k_node,  dim3(512),  dim3(256), 0, stream, nf, degf, B, gcn_w, gcn_b, S, T2, NN);
        hipLaunchKernelGGL(k_final, dim3(1),    dim3(128), 0, stream,
                           S, T2, esn, ln_w, ln_b, fc1_w, fc1_b, fc2_w, fc2_b, out);
    }
}

// Round 12
// 66.119 us; speedup vs baseline: 2.8366x; 2.1760x over previous
//
#include <hip/hip_runtime.h>
#include <math.h>

#define NN 100000
#define EE 1600000
#define HH 128
#define RR 500
#define AA 16
#define LN_EPS 1e-5f

// Bucketing: nodes -> 391 buckets of 256; payload packs (src<<8 | dst&255) in u32.
#define BSH 8
#define NPB 256
#define NB 391                   // ceil(100000/256)
#define MAXPB 4608               // mean 4096, +8 sigma
#define EPW 8192                 // edges per scatter workgroup (r8-proven)
#define SCT 512                  // scatter threads
#define NWG_SC ((EE + EPW - 1) / EPW)   // 196
#define NZW 64                   // zpart slices (8 k-rows each, covers 500)

// WG0: zero gctr/S/T2/done. WGs 1..64: zpart[w][ch] = sum_k esn[k]*fc1_w[(HH+k)*HH+ch].
__global__ __launch_bounds__(256) void k_init_esn(unsigned int* __restrict__ zero_region,
                                                  const float* __restrict__ esn,
                                                  const float* __restrict__ fc1_w,
                                                  float* __restrict__ zpart) {
    const int w = blockIdx.x, t = threadIdx.x;
    if (w == 0) {
        for (int j = t; j < 642; j += 256) zero_region[j] = 0u;   // gctr|S|T2|done
        return;
    }
    const int sl = w - 1;                 // 0..63
    const int k0 = sl * 8;
    const int k1 = min(k0 + 8, RR);
    if (t < HH) {
        float acc = 0.f;
        for (int k = k0; k < k1; ++k)
            acc = fmaf(esn[k], fc1_w[(size_t)(HH + k) * HH + t], acc);
        zpart[(size_t)sl * HH + t] = acc;
    }
}

// Bucket edges by dst: LDS bucket histogram -> one reserve atomic per (WG,bucket)
// -> per-edge LDS rank atomic + direct global payload write.
__global__ __launch_bounds__(SCT) void k_scatter(const int* __restrict__ src,
                                                 const int* __restrict__ dst,
                                                 unsigned int* __restrict__ gctr,
                                                 unsigned int* __restrict__ payload) {
    __shared__ unsigned int hist[512], rank[512], hbase[512];
    const int t = threadIdx.x;
    hist[t] = 0u; rank[t] = 0u; hbase[t] = 0u;
    __syncthreads();
    const int e0 = blockIdx.x * EPW;
    const int ecnt = max(0, min(EPW, EE - e0));   // mult of 4
    const int nv = ecnt >> 2;
    const int4* d4 = reinterpret_cast<const int4*>(dst + e0);
    const int4* s4 = reinterpret_cast<const int4*>(src + e0);

    for (int k = t; k < nv; k += SCT) {
        int4 d = d4[k];
        atomicAdd(&hist[((unsigned)d.x) >> BSH], 1u);
        atomicAdd(&hist[((unsigned)d.y) >> BSH], 1u);
        atomicAdd(&hist[((unsigned)d.z) >> BSH], 1u);
        atomicAdd(&hist[((unsigned)d.w) >> BSH], 1u);
    }
    __syncthreads();

    if (t < NB && hist[t] > 0u) hbase[t] = atomicAdd(&gctr[t], hist[t]);
    __syncthreads();

    for (int k = t; k < nv; k += SCT) {
        int4 d = d4[k];
        int4 s = s4[k];
        #define EMIT(SS, DD) { \
            unsigned int dd = (unsigned)(DD), ss = (unsigned)(SS); \
            unsigned int b = dd >> BSH; \
            unsigned int r = atomicAdd(&rank[b], 1u); \
            unsigned int slot = hbase[b] + r; \
            if (slot < MAXPB) payload[(size_t)b * MAXPB + slot] = (ss << BSH) | (dd & (NPB - 1)); }
        EMIT(s.x, d.x) EMIT(s.y, d.y) EMIT(s.z, d.z) EMIT(s.w, d.w)
        #undef EMIT
    }
}

// Per bucket, 1024 threads: LDS degree histogram; write rsv = rsqrt(deg), g = rsv*f.
__global__ __launch_bounds__(1024) void k_bdeg_g(const unsigned int* __restrict__ gctr,
                                                 const unsigned int* __restrict__ payload,
                                                 const float* __restrict__ nf,
                                                 float* __restrict__ rsv, float* __restrict__ g) {
    __shared__ unsigned int hist[NPB];
    const int b = blockIdx.x, t = threadIdx.x;
    if (t < NPB) hist[t] = 0u;
    __syncthreads();
    const unsigned int cnt = min(gctr[b], (unsigned int)MAXPB);
    const unsigned int* pl = payload + (size_t)b * MAXPB;
    const uint4* pl4 = reinterpret_cast<const uint4*>(pl);
    const unsigned int nv = cnt >> 2;
    for (unsigned int k = t; k < nv; k += 1024) {
        uint4 p = pl4[k];
        atomicAdd(&hist[p.x & (NPB - 1)], 1u);
        atomicAdd(&hist[p.y & (NPB - 1)], 1u);
        atomicAdd(&hist[p.z & (NPB - 1)], 1u);
        atomicAdd(&hist[p.w & (NPB - 1)], 1u);
    }
    for (unsigned int k = (nv << 2) + t; k < cnt; k += 1024)
        atomicAdd(&hist[pl[k] & (NPB - 1)], 1u);
    __syncthreads();
    if (t < NPB) {
        int node = (b << BSH) + t;
        if (node < NN) {
            float df = 1.0f + (float)hist[t];
            float rs = rsqrtf(df);
            rsv[node] = rs;
            float2 f = *reinterpret_cast<const float2*>(&nf[2 * node]);
            float2 gv; gv.x = rs * f.x; gv.y = rs * f.y;
            *reinterpret_cast<float2*>(&g[2 * node]) = gv;
        }
    }
}

// Per bucket, 1024 threads: aggregate g[src] into x/y LDS planes, fold self-loop,
// GCN channel pass + relu; atomic S/T2; LAST block runs the FC tail in-place.
// NOTE: no __threadfence() — the compiler-emitted vmcnt(0) drain at __syncthreads
// plus memory-side atomic ordering already make S/T2 visible to the last block.
// An explicit device fence here compiles to an L2 invalidate executed by every
// block and cost 100 µs in round 11 (invalidation storm).
__global__ __launch_bounds__(1024) void k_bagg_node(const unsigned int* __restrict__ gctr,
        const unsigned int* __restrict__ payload,
        const float* __restrict__ g, const float* __restrict__ rsv,
        const float* __restrict__ gcn_w, const float* __restrict__ gcn_b,
        float* __restrict__ S, float* __restrict__ T2, unsigned int* __restrict__ done,
        const float* __restrict__ zpart,
        const float* __restrict__ ln_w, const float* __restrict__ ln_b,
        const float* __restrict__ fc1_w, const float* __restrict__ fc1_b,
        const float* __restrict__ fc2_w, const float* __restrict__ fc2_b,
        float* __restrict__ out) {
    __shared__ union {
        struct { float agg[NPB * 2]; float shSf[HH]; float shw[16]; } ba;
        struct { float psum[8][HH]; float pooled[HH]; float z[HH];
                 float logits[AA]; float red[2]; } fin;
    } u;
    __shared__ int s_last;
    const int b = blockIdx.x, t = threadIdx.x;
    if (t < NPB * 2) u.ba.agg[t] = 0.f;
    if (t < HH) u.ba.shSf[t] = 0.f;
    __syncthreads();
    const unsigned int cnt = min(gctr[b], (unsigned int)MAXPB);
    const unsigned int* pl = payload + (size_t)b * MAXPB;
    const uint4* pl4 = reinterpret_cast<const uint4*>(pl);
    const unsigned int nv = cnt >> 2;
    for (unsigned int k = t; k < nv; k += 1024) {
        uint4 p = pl4[k];
        #define ACC(P) { \
            unsigned int s = (P) >> BSH, dl = (P) & (NPB - 1); \
            float2 gv = *reinterpret_cast<const float2*>(&g[2 * s]); \
            atomicAdd(&u.ba.agg[dl],       gv.x); \
            atomicAdd(&u.ba.agg[NPB + dl], gv.y); }
        ACC(p.x) ACC(p.y) ACC(p.z) ACC(p.w)
        #undef ACC
    }
    for (unsigned int k = (nv << 2) + t; k < cnt; k += 1024) {
        unsigned int p = pl[k];
        unsigned int s = p >> BSH, dl = p & (NPB - 1);
        float2 gv = *reinterpret_cast<const float2*>(&g[2 * s]);
        atomicAdd(&u.ba.agg[dl],       gv.x);
        atomicAdd(&u.ba.agg[NPB + dl], gv.y);
    }
    __syncthreads();

    const int nvalid = min(NPB, NN - (b << BSH));
    if (t < nvalid) {
        int node = (b << BSH) + t;
        float rs = rsv[node];
        float2 gv = *reinterpret_cast<const float2*>(&g[2 * node]);
        u.ba.agg[t]       = rs * (u.ba.agg[t]       + gv.x);
        u.ba.agg[NPB + t] = rs * (u.ba.agg[NPB + t] + gv.y);
    }
    __syncthreads();

    const int ch = t & (HH - 1), slot = t >> 7;
    {
        const float w0 = gcn_w[ch], w1 = gcn_w[HH + ch], bb = gcn_b[ch];
        float accS = 0.f, accT2 = 0.f;
        for (int j = slot; j < nvalid; j += 8) {
            float x = fmaf(u.ba.agg[j], w0, fmaf(u.ba.agg[NPB + j], w1, bb));
            float r = fmaxf(x, 0.f);
            accS  += r;
            accT2 += r * r;
        }
        atomicAdd(&u.ba.shSf[ch], accS);
        float v = accT2;
        for (int o = 32; o; o >>= 1) v += __shfl_down(v, o, 64);
        if ((t & 63) == 0) u.ba.shw[t >> 6] = v;
        __syncthreads();
        if (t < HH) atomicAdd(&S[t], u.ba.shSf[t]);
        if (t == 0) {
            float s2 = 0.f;
            #pragma unroll
            for (int w = 0; w < 16; ++w) s2 += u.ba.shw[w];
            atomicAdd(T2, s2);
        }
    }
    // ---- last-block election (S/T2 adds drained by syncthreads' vmcnt wait) ----
    __syncthreads();
    if (t == 0) {
        unsigned int old = atomicAdd(done, 1u);
        s_last = (old == NB - 1) ? 1 : 0;
    }
    __syncthreads();
    if (!s_last) return;

    // ---- tail (r8 k_final2 body), agent-scope atomic loads for S/T2 ----
    const int sl = t >> 7;
    if (t < HH) {
        float s = __hip_atomic_load(&S[t], __ATOMIC_RELAXED, __HIP_MEMORY_SCOPE_AGENT);
        u.fin.pooled[t] = s;
        float vv = s;
        for (int o = 32; o; o >>= 1) vv += __shfl_down(vv, o, 64);
        if ((t & 63) == 0) u.fin.red[t >> 6] = vv;
    }
    __syncthreads();
    const float T1 = u.fin.red[0] + u.fin.red[1];
    const float T2v = __hip_atomic_load(T2, __ATOMIC_RELAXED, __HIP_MEMORY_SCOPE_AGENT);
    const float cntf = (float)NN * (float)HH;
    const float mean = T1 / cntf;
    const float var  = T2v / cntf - mean * mean;
    const float denom = sqrtf(var) + LN_EPS;
    if (t < HH)
        u.fin.pooled[t] = ln_w[t] * (u.fin.pooled[t] - (float)NN * mean) / denom + (float)NN * ln_b[t];
    __syncthreads();

    float acc = 0.f;
    for (int k = sl * 16; k < sl * 16 + 16; ++k)
        acc = fmaf(u.fin.pooled[k], fc1_w[(size_t)k * HH + ch], acc);
    for (int w = sl * 8; w < sl * 8 + 8; ++w)
        acc += zpart[(size_t)w * HH + ch];
    u.fin.psum[sl][ch] = acc;
    __syncthreads();
    if (t < HH) {
        float a = fc1_b[t];
        #pragma unroll
        for (int k = 0; k < 8; ++k) a += u.fin.psum[k][t];
        u.fin.z[t] = fmaxf(a, 0.f);
    }
    __syncthreads();

    if (t < AA) {
        float l = fc2_b[t];
        for (int j = 0; j < HH; ++j)
            l = fmaf(u.fin.z[j], fc2_w[j * AA + t], l);
        u.fin.logits[t] = l;
    }
    __syncthreads();

    if (t == 0) {
        float m = u.fin.logits[0];
        for (int a = 1; a < AA; ++a) m = fmaxf(m, u.fin.logits[a]);
        float sum = 0.f;
        for (int a = 0; a < AA; ++a) sum += expf(u.fin.logits[a] - m);
        float lse = m + logf(sum);
        for (int a = 0; a < AA; ++a) out[a] = u.fin.logits[a] - lse;
    }
}

// ---------------- fallback path (round-2 known-good) ----------------

__global__ void k_initf(unsigned int* __restrict__ p, int n) {
    int i = blockIdx.x * blockDim.x + threadIdx.x;
    int stride = gridDim.x * blockDim.x;
    for (int j = i; j < n; j += stride) p[j] = 0u;
}

__global__ void k_deg1(const int* __restrict__ dst, int* __restrict__ deg, int e) {
    int i = blockIdx.x * blockDim.x + threadIdx.x;
    if (i < e) atomicAdd(&deg[dst[i]], 1);
}

__global__ void k_g1(const int* __restrict__ deg, const float* __restrict__ nf,
                     float* __restrict__ degf, float* __restrict__ g, int n) {
    int i = blockIdx.x * blockDim.x + threadIdx.x;
    if (i < n) {
        float df = (float)(1 + deg[i]);
        degf[i] = df;
        float rs = rsqrtf(df);
        float2 f = *reinterpret_cast<const float2*>(&nf[2 * i]);
        float2 gv; gv.x = rs * f.x; gv.y = rs * f.y;
        *reinterpret_cast<float2*>(&g[2 * i]) = gv;
    }
}

__global__ void k_edge1(const int* __restrict__ src, const int* __restrict__ dst,
                        const float* __restrict__ g, float* __restrict__ B, int e) {
    int i = blockIdx.x * blockDim.x + threadIdx.x;
    if (i < e) {
        int s = src[i], d = dst[i];
        float2 gv = *reinterpret_cast<const float2*>(&g[2 * s]);
        atomicAdd(&B[2 * d],     gv.x);
        atomicAdd(&B[2 * d + 1], gv.y);
    }
}

__global__ void k_node(const float* __restrict__ nf, const float* __restrict__ degf,
                       const float* __restrict__ B,
                       const float* __restrict__ gcn_w, const float* __restrict__ gcn_b,
                       float* __restrict__ S, float* __restrict__ T2, int n) {
    const int ch   = threadIdx.x & (HH - 1);
    const int slot = threadIdx.x >> 7;
    const float w0 = gcn_w[ch];
    const float w1 = gcn_w[HH + ch];
    const float b  = gcn_b[ch];
    float accS = 0.f, accT2 = 0.f;
    for (int i = blockIdx.x * 2 + slot; i < n; i += gridDim.x * 2) {
        float df   = degf[i];
        float invd = 1.0f / df;
        float rs   = rsqrtf(df);
        float2 bv = *reinterpret_cast<const float2*>(&B[2 * i]);
        float2 f  = *reinterpret_cast<const float2*>(&nf[2 * i]);
        float b0 = rs * bv.x + f.x * invd;
        float b1 = rs * bv.y + f.y * invd;
        float xv = fmaf(b0, w0, fmaf(b1, w1, b));
        float r  = fmaxf(xv, 0.f);
        accS  += r;
        accT2 += r * r;
    }
    __shared__ float shS[HH];
    if (slot == 1) shS[ch] = accS;
    __syncthreads();
    if (slot == 0) atomicAdd(&S[ch], accS + shS[ch]);
    float v = accT2;
    for (int o = 32; o; o >>= 1) v += __shfl_down(v, o, 64);
    __shared__ float shw[4];
    if ((threadIdx.x & 63) == 0) shw[threadIdx.x >> 6] = v;
    __syncthreads();
    if (threadIdx.x == 0) atomicAdd(T2, shw[0] + shw[1] + shw[2] + shw[3]);
}

__global__ void k_final(const float* __restrict__ S, const float* __restrict__ T2ptr,
                        const float* __restrict__ esn,
                        const float* __restrict__ ln_w, const float* __restrict__ ln_b,
                        const float* __restrict__ fc1_w, const float* __restrict__ fc1_b,
                        const float* __restrict__ fc2_w, const float* __restrict__ fc2_b,
                        float* __restrict__ out) {
    const int t = threadIdx.x;
    __shared__ float sh_pooled[HH];
    __shared__ float sh_z[HH];
    __shared__ float sh_logits[AA];
    __shared__ float shred[2];

    float s = S[t];
    float v = s;
    for (int o = 32; o; o >>= 1) v += __shfl_down(v, o, 64);
    if ((t & 63) == 0) shred[t >> 6] = v;
    __syncthreads();
    const float T1 = shred[0] + shred[1];
    const float T2 = *T2ptr;
    const float cnt = (float)NN * (float)HH;
    const float mean = T1 / cnt;
    const float var  = T2 / cnt - mean * mean;
    const float denom = sqrtf(var) + LN_EPS;
    sh_pooled[t] = ln_w[t] * (s - (float)NN * mean) / denom + (float)NN * ln_b[t];
    __syncthreads();

    float acc = fc1_b[t];
    for (int k = 0; k < HH; ++k)
        acc = fmaf(sh_pooled[k], fc1_w[k * HH + t], acc);
    for (int k = 0; k < RR; ++k)
        acc = fmaf(esn[k], fc1_w[(HH + k) * HH + t], acc);
    sh_z[t] = fmaxf(acc, 0.f);
    __syncthreads();

    if (t < AA) {
        float l = fc2_b[t];
        for (int j = 0; j < HH; ++j)
            l = fmaf(sh_z[j], fc2_w[j * AA + t], l);
        sh_logits[t] = l;
    }
    __syncthreads();

    if (t == 0) {
        float m = sh_logits[0];
        for (int a = 1; a < AA; ++a) m = fmaxf(m, sh_logits[a]);
        float sum = 0.f;
        for (int a = 0; a < AA; ++a) sum += expf(sh_logits[a] - m);
        float lse = m + logf(sum);
        for (int a = 0; a < AA; ++a) out[a] = sh_logits[a] - lse;
    }
}

extern "C" void kernel_launch(void* const* d_in, const int* in_sizes, int n_in,
                              void* d_out, int out_size, void* d_ws, size_t ws_size,
                              hipStream_t stream) {
    const float* nf     = (const float*)d_in[0];
    const int*   ei     = (const int*)d_in[1];
    const float* esn    = (const float*)d_in[2];
    const float* gcn_w  = (const float*)d_in[3];
    const float* gcn_b  = (const float*)d_in[4];
    const float* ln_w   = (const float*)d_in[5];
    const float* ln_b   = (const float*)d_in[6];
    const float* fc1_w  = (const float*)d_in[7];
    const float* fc1_b  = (const float*)d_in[8];
    const float* fc2_w  = (const float*)d_in[9];
    const float* fc2_b  = (const float*)d_in[10];
    float* out = (float*)d_out;
    float* ws  = (float*)d_ws;

    // Layout (word offsets):
    //   gctr:0(512) | S:512(128) | T2:640 | done:641 | zpart:644(64*128) | payload | rsv | g
    const size_t OFF_S       = 512;
    const size_t OFF_T2      = OFF_S + HH;                          // 640
    const size_t OFF_DONE    = OFF_T2 + 1;                          // 641
    const size_t OFF_ZPART   = 644;
    const size_t OFF_PAYLOAD = OFF_ZPART + (size_t)NZW * HH;        // 8836 (mult of 4)
    const size_t OFF_RSV     = OFF_PAYLOAD + (size_t)NB * MAXPB;
    const size_t OFF_G       = OFF_RSV + NN;                        // even -> float2 ok
    const size_t NEED_BKT    = (OFF_G + 2 * (size_t)NN) * 4;

    if (ws_size >= NEED_BKT) {
        unsigned int* gctr    = (unsigned int*)ws;
        float*        S       = ws + OFF_S;
        float*        T2      = ws + OFF_T2;
        unsigned int* done    = (unsigned int*)ws + OFF_DONE;
        float*        zpart   = ws + OFF_ZPART;
        unsigned int* payload = (unsigned int*)ws + OFF_PAYLOAD;
        float*        rsv     = ws + OFF_RSV;
        float*        g       = ws + OFF_G;

        hipLaunchKernelGGL(k_init_esn,  dim3(NZW + 1), dim3(256),  0, stream, (unsigned int*)ws, esn, fc1_w, zpart);
        hipLaunchKernelGGL(k_scatter,   dim3(NWG_SC),  dim3(SCT),  0, stream, ei, ei + EE, gctr, payload);
        hipLaunchKernelGGL(k_bdeg_g,    dim3(NB),      dim3(1024), 0, stream, gctr, payload, nf, rsv, g);
        hipLaunchKernelGGL(k_bagg_node, dim3(NB),      dim3(1024), 0, stream,
                           gctr, payload, g, rsv, gcn_w, gcn_b, S, T2, done, zpart,
                           ln_w, ln_b, fc1_w, fc1_b, fc2_w, fc2_b, out);
    } else {
        // Fallback: known-good atomic path.
        int*   deg  = (int*)ws;
        float* B    = ws + NN;
        float* S    = ws + 3 * (size_t)NN;
        float* T2   = ws + 3 * (size_t)NN + 128;
        float* degf = ws + 3 * (size_t)NN + 130;
        float* g    = ws + 4 * (size_t)NN + 130;
        const int eb = (EE + 255) / 256;
        const int nb = (NN + 255) / 256;
        hipLaunchKernelGGL(k_initf, dim3(2048), dim3(256), 0, stream, (unsigned int*)ws, 3 * NN + 129);
        hipLaunchKernelGGL(k_deg1,  dim3(eb),   dim3(256), 0, stream, ei + EE, deg, EE);
        hipLaunchKernelGGL(k_g1,    dim3(nb),   dim3(256), 0, stream, deg, nf, degf, g, NN);
        hipLaunchKernelGGL(k_edge1, dim3(eb),   dim3(256), 0, stream, ei, ei + EE, g, B, EE);
        hipLaunchKernelGGL(k_node,  dim3(512),  dim3(256), 0, stream, nf, degf, B, gcn_w, gcn_b, S, T2, NN);
        hipLaunchKernelGGL(k_final, dim3(1),    dim3(128), 0, stream,
                           S, T2, esn, ln_w, ln_b, fc1_w, fc1_b, fc2_w, fc2_b, out);
    }
}